// Round 20
// baseline (185.229 us; speedup 1.0000x reference)
//
#include <hip/hip_runtime.h>
#include <stdint.h>

using bf16   = __bf16;
using bf16x4 = __attribute__((ext_vector_type(4))) __bf16;
using bf16x8 = __attribute__((ext_vector_type(8))) __bf16;
using f32x4  = __attribute__((ext_vector_type(4))) float;

#define DEPTH   11
#define NTREES  16
#define DM      256
#define PER     4095      // 2^12 - 1 nodes per tree
#define KDIM    512       // 2*DM
#define NGATES  5

__device__ __forceinline__ float sigf(float x) { return 1.0f / (1.0f + __expf(-x)); }
__device__ __forceinline__ float tanh_fast(float x) {
    float e = __expf(2.0f * x);
    return 1.0f - 2.0f / (e + 1.0f);   // safe at +/-inf
}

__device__ __forceinline__ void load_lds16(const bf16* g, bf16* l) {
    __builtin_amdgcn_global_load_lds((const __attribute__((address_space(1))) void*)g,
                                     (__attribute__((address_space(3))) void*)l,
                                     16, 0, 0);
}

// Fused setup kernel. Blocks [0,320): Wfrag repack; blocks [320, 8512): leaf
// embedding. Outputs disjoint; no ordering needed between the two halves.
__global__ __launch_bounds__(256) void setup_kernel(
        const float* __restrict__ W, bf16* __restrict__ Wf,
        const int* __restrict__ tokens, const float* __restrict__ emb,
        float* acts, bf16* actsb) {
    int bid = blockIdx.x;
    if (bid < 320) {
        int tid = bid * 256 + threadIdx.x;          // 0 .. 81919
        int f   = tid >> 6;                         // fragment id 0..1279
        int l   = tid & 63;
        int gt  = f >> 4;
        int ks  = f & 15;
        int n   = (gt << 4) + (l & 15);
        int k0  = (ks << 5) + ((l >> 4) << 3);
        bf16x8 v;
        #pragma unroll
        for (int e = 0; e < 8; ++e) v[e] = (bf16)W[(size_t)(k0 + e) * 1280 + n];
        *reinterpret_cast<bf16x8*>(Wf + (size_t)tid * 8) = v;
        return;
    }
    int wid  = ((bid - 320) * 256 + threadIdx.x) >> 6;  // leaf index 0..32767
    int lane = threadIdx.x & 63;
    int b    = wid >> 11;
    int loc  = wid & 2047;
    int id   = b * PER + loc;
    int tok  = tokens[id];

    float4 e = *reinterpret_cast<const float4*>(emb + tok * DM + lane * 4);
    float ss = e.x * e.x + e.y * e.y + e.z * e.z + e.w * e.w;
    #pragma unroll
    for (int off = 32; off; off >>= 1) ss += __shfl_xor(ss, off);
    float scale = fminf(1.0f, 1.0f / fmaxf(sqrtf(ss), 1e-7f));
    e.x *= scale; e.y *= scale; e.z *= scale; e.w *= scale;

    int o = id * DM + lane * 4;
    *reinterpret_cast<float4*>(acts + o) = e;
    bf16x4 eb;
    eb.x = (bf16)e.x; eb.y = (bf16)e.y; eb.z = (bf16)e.z; eb.w = (bf16)e.w;
    *reinterpret_cast<bf16x4*>(actsb + o) = eb;
}

// ---------- Big-level kernel (Mt >= 128): R13 structure + COALESCED EPILOGUE
// Block: 256 thr (4 waves). Tile: 64 rows x 64 ucols (x 5 gates).
// LDS: A dbuf [2][16][64][8] bf16 = 32 KB, ALIASED after the K-loop as
// ldsH[64][68] + ldsC[64][68] f32 (34.8 KB union) for the epilogue bounce.
// Epilogue: acc -> LDS (padded, ~2-way max) -> cooperative write-out where
// 4 consecutive threads emit 256 B contiguous f32 per row (acts, mem) and
// 128 B contiguous bf16 (actsb): full-line HBM writes instead of the MFMA
// C-layout's 16x64B scatter (the invariant that pinned all 7 schedule
// variants at 1.6-1.9 TB/s effective).
__global__ __launch_bounds__(256, 2) void level_big(
        const bf16* __restrict__ actsb_in, const bf16* __restrict__ Wfrag,
        const float* __restrict__ bias, float* __restrict__ mem,
        float* __restrict__ acts, bf16* __restrict__ actsb_out,
        int off_k, int off_km1, int zmem) {
    constexpr int RPB = 64;
    constexpr int NRG = 4;                 // row groups per wave
    constexpr int NLD = 4;                 // global_load_lds per K-step (BK=128)
    __shared__ __align__(16) char ldsbuf[2 * 64 * 68 * 4];   // 34,816 B union
    bf16*  ldsA = reinterpret_cast<bf16*>(ldsbuf);           // [2][16][64][8]
    float* ldsH = reinterpret_cast<float*>(ldsbuf);          // [64][68]
    float* ldsC = ldsH + 64 * 68;                            // [64][68]

    int t    = threadIdx.x;
    int lane = t & 63;
    int w    = t >> 6;
    int lo   = lane & 15;
    int hi   = lane >> 4;          // 0..3

    int rt    = blockIdx.x >> 2;   // 64-row tile within tree
    int uct   = blockIdx.x & 3;    // ucol tile (64 of 256)
    int b     = blockIdx.y;        // tree
    int rm    = rt * RPB;
    int wslot = (uct << 2) + w;    // 0..15: this wave's 16-ucol slot

    const bf16* Abase = actsb_in + (size_t)(b * PER + off_km1) * DM;

    const bf16* aSrc[NLD];
    #pragma unroll
    for (int i = 0; i < NLD; ++i) {
        int s   = i * 256 + t;
        aSrc[i] = Abase + (size_t)(rm + (s & (RPB - 1))) * KDIM + (s / RPB) * 8;
    }

    const bf16* bbase = Wfrag + ((size_t)wslot << 13) + lane * 8;

    int ucol = (wslot << 4) + lo;
    float bi[NGATES];
    #pragma unroll
    for (int g = 0; g < NGATES; ++g) bi[g] = bias[g * DM + ucol];

    #pragma unroll
    for (int i = 0; i < NLD; ++i)
        load_lds16(aSrc[i], ldsA + (i * 256 + t) * 8);

    f32x4 acc[NGATES][NRG] = {};

    __syncthreads();

    for (int kt = 0; kt < 4; ++kt) {
        int cur = kt & 1;
        if (kt < 3) {                              // prefetch next K-tile (A)
            int ko = (kt + 1) * 128;
            #pragma unroll
            for (int i = 0; i < NLD; ++i)
                load_lds16(aSrc[i] + ko, ldsA + (cur ^ 1) * 8192 + (i * 256 + t) * 8);
        }

        #pragma unroll
        for (int kq = 0; kq < 4; ++kq) {           // 4 x 32-k slices
            bf16x8 bb[NGATES];
            #pragma unroll
            for (int g = 0; g < NGATES; ++g)
                bb[g] = *reinterpret_cast<const bf16x8*>(bbase + (size_t)(((g << 8) | ((kt << 2) + kq)) << 9));
            #pragma unroll
            for (int rg = 0; rg < NRG; ++rg) {
                const bf16* ap = ldsA + cur * 8192 + (((kq << 2) + hi) * RPB + (rg << 4) + lo) * 8;
                bf16x8 af = *reinterpret_cast<const bf16x8*>(ap);
                #pragma unroll
                for (int g = 0; g < NGATES; ++g)
                    acc[g][rg] = __builtin_amdgcn_mfma_f32_16x16x32_bf16(af, bb[g], acc[g][rg], 0, 0, 0);
            }
        }
        __syncthreads();
    }
    // K-loop done; all ldsA reads complete (barrier above). Alias as ldsH/ldsC.

    int treebase = b * PER;
    int cw = (w << 4) + lo;                        // col within 64-ucol band
    #pragma unroll
    for (int rg = 0; rg < NRG; ++rg) {
        #pragma unroll
        for (int r = 0; r < 4; ++r) {
            int rl = (rg << 4) + (hi << 2) + r;    // row within 64-row tile
            int ml = rm + rl;
            float cl = 0.0f, cr = 0.0f;
            if (!zmem) {
                int ch = (treebase + off_km1 + (ml << 1)) * DM + ucol;
                cl = mem[ch];
                cr = mem[ch + DM];
            }
            float gi = acc[0][rg][r] + bi[0];
            float gl = acc[1][rg][r] + bi[1];
            float gr = acc[2][rg][r] + bi[2];
            float go = acc[3][rg][r] + bi[3];
            float gu = acc[4][rg][r] + bi[4];
            float c  = sigf(gi) * tanh_fast(gu) + sigf(gl) * cl + sigf(gr) * cr;
            float h  = sigf(go) * tanh_fast(c);
            ldsH[rl * 68 + cw] = h;
            ldsC[rl * 68 + cw] = c;
        }
    }
    __syncthreads();

    // Cooperative coalesced write-out: thread t -> row rl = t>>2, quarter q.
    {
        int rl = t >> 2;
        int q  = t & 3;
        int id = treebase + off_k + rm + rl;
        size_t gb = (size_t)id * DM + (uct << 6) + (q << 4);
        const float* hrow = ldsH + rl * 68 + (q << 4);
        const float* crow = ldsC + rl * 68 + (q << 4);
        bf16 hb[16];
        #pragma unroll
        for (int j = 0; j < 4; ++j) {
            float4 hv = *reinterpret_cast<const float4*>(hrow + j * 4);
            float4 cv = *reinterpret_cast<const float4*>(crow + j * 4);
            *reinterpret_cast<float4*>(acts + gb + j * 4) = hv;
            *reinterpret_cast<float4*>(mem  + gb + j * 4) = cv;
            hb[j * 4 + 0] = (bf16)hv.x; hb[j * 4 + 1] = (bf16)hv.y;
            hb[j * 4 + 2] = (bf16)hv.z; hb[j * 4 + 3] = (bf16)hv.w;
        }
        *reinterpret_cast<bf16x8*>(actsb_out + gb)     = *reinterpret_cast<bf16x8*>(&hb[0]);
        *reinterpret_cast<bf16x8*>(actsb_out + gb + 8) = *reinterpret_cast<bf16x8*>(&hb[8]);
    }
}

// ---------- Split-K tail kernel (Mt < 128): 8-way K-split, 512 thr ----------
__global__ __launch_bounds__(512) void level_splitk(
        const bf16* __restrict__ actsb_in, const bf16* __restrict__ Wfrag,
        const float* __restrict__ bias, float* mem, float* acts, bf16* actsb_out,
        int off_k, int off_km1, int shift) {
    __shared__ f32x4 red[7][NGATES][64];

    int t    = threadIdx.x;
    int lane = t & 63;
    int w    = t >> 6;                 // 0..7
    int lo   = lane & 15;
    int hi   = lane >> 4;
    int tile = blockIdx.x >> 4;        // 16-row tile
    int uc   = blockIdx.x & 15;        // 16-ucol tile
    int m0   = tile << 4;
    int mask = (1 << shift) - 1;

    int mA   = m0 + lo;
    int rowA = (mA >> shift) * PER + off_km1 + ((mA & mask) << 1);
    const bf16* aptr  = actsb_in + (size_t)rowA * DM + hi * 8 + (w << 1) * 32;
    const bf16* bbase = Wfrag + ((size_t)uc << 13) + lane * 8;

    f32x4 acc[NGATES] = {};
    #pragma unroll
    for (int kk = 0; kk < 2; ++kk) {
        int kt = (w << 1) + kk;
        bf16x8 a = *reinterpret_cast<const bf16x8*>(aptr + kk * 32);
        #pragma unroll
        for (int g = 0; g < NGATES; ++g) {
            bf16x8 bb = *reinterpret_cast<const bf16x8*>(bbase + (size_t)(((g << 8) + kt) << 9));
            acc[g] = __builtin_amdgcn_mfma_f32_16x16x32_bf16(a, bb, acc[g], 0, 0, 0);
        }
    }

    if (w) {
        #pragma unroll
        for (int g = 0; g < NGATES; ++g) red[w - 1][g][lane] = acc[g];
    }
    __syncthreads();
    if (w == 0) {
        int ucol = (uc << 4) + lo;
        float bi[NGATES];
        #pragma unroll
        for (int g = 0; g < NGATES; ++g) {
            #pragma unroll
            for (int p = 0; p < 7; ++p) acc[g] += red[p][g][lane];
            bi[g] = bias[g * DM + ucol];
        }
        #pragma unroll
        for (int r = 0; r < 4; ++r) {
            int m   = m0 + (hi << 2) + r;
            int tb  = (m >> shift) * PER;
            int loc = m & mask;
            int id  = tb + off_k + loc;
            int ch  = (tb + off_km1 + (loc << 1)) * DM + ucol;
            float cl = mem[ch];
            float cr = mem[ch + DM];
            float gi = acc[0][r] + bi[0];
            float gl = acc[1][r] + bi[1];
            float gr = acc[2][r] + bi[2];
            float go = acc[3][r] + bi[3];
            float gu = acc[4][r] + bi[4];
            float c  = sigf(gi) * tanh_fast(gu) + sigf(gl) * cl + sigf(gr) * cr;
            float h  = sigf(go) * tanh_fast(c);
            int oi = id * DM + ucol;
            acts[oi]      = h;
            mem[oi]       = c;
            actsb_out[oi] = (bf16)h;
        }
    }
}

extern "C" void kernel_launch(void* const* d_in, const int* in_sizes, int n_in,
                              void* d_out, int out_size, void* d_ws, size_t ws_size,
                              hipStream_t stream) {
    (void)in_sizes; (void)n_in; (void)out_size; (void)ws_size;
    const int*   tokens = (const int*)d_in[0];
    const float* emb    = (const float*)d_in[8];
    const float* W      = (const float*)d_in[9];
    const float* bias   = (const float*)d_in[10];
    float* acts = (float*)d_out;

    char* ws = (char*)d_ws;
    bf16*  Wfrag = (bf16*)ws;                               // 1,310,720 B
    bf16*  actsb = (bf16*)(ws + 1310720);                   // 33,546,240 B
    float* mem   = (float*)(ws + 1310720 + 33546240);       // 67,092,480 B

    setup_kernel<<<dim3(320 + 8192), dim3(256), 0, stream>>>(
        W, Wfrag, tokens, emb, acts, actsb);

    int off_km1 = 0;
    for (int k = 1; k <= DEPTH; ++k) {
        int shift   = DEPTH - k;
        int Mt      = 1 << shift;            // rows per tree at this level
        int off_k   = off_km1 + (Mt << 1);
        int M_total = NTREES << shift;
        if (Mt >= 128) {
            level_big<<<dim3((Mt / 64) * 4, NTREES), dim3(256), 0, stream>>>(
                actsb, Wfrag, bias, mem, acts, actsb, off_k, off_km1, (k == 1) ? 1 : 0);
        } else {
            level_splitk<<<dim3(M_total), dim3(512), 0, stream>>>(
                actsb, Wfrag, bias, mem, acts, actsb, off_k, off_km1, shift);
        }
        off_km1 = off_k;
    }
}

// Round 21
// 166.244 us; speedup vs baseline: 1.1142x; 1.1142x over previous
//
#include <hip/hip_runtime.h>
#include <stdint.h>

using bf16   = __bf16;
using bf16x4 = __attribute__((ext_vector_type(4))) __bf16;
using bf16x8 = __attribute__((ext_vector_type(8))) __bf16;
using f32x4  = __attribute__((ext_vector_type(4))) float;

#define DEPTH   11
#define NTREES  16
#define DM      256
#define PER     4095      // 2^12 - 1 nodes per tree
#define KDIM    512       // 2*DM
#define NGATES  5

__device__ __forceinline__ float sigf(float x) { return 1.0f / (1.0f + __expf(-x)); }
__device__ __forceinline__ float tanh_fast(float x) {
    float e = __expf(2.0f * x);
    return 1.0f - 2.0f / (e + 1.0f);   // safe at +/-inf
}

__device__ __forceinline__ void load_lds16(const bf16* g, bf16* l) {
    __builtin_amdgcn_global_load_lds((const __attribute__((address_space(1))) void*)g,
                                     (__attribute__((address_space(3))) void*)l,
                                     16, 0, 0);
}

// Fused setup kernel. Blocks [0,320): Wfrag repack; blocks [320, 8512): leaf
// embedding. Outputs disjoint; no ordering needed between the two halves.
__global__ __launch_bounds__(256) void setup_kernel(
        const float* __restrict__ W, bf16* __restrict__ Wf,
        const int* __restrict__ tokens, const float* __restrict__ emb,
        float* acts, bf16* actsb) {
    int bid = blockIdx.x;
    if (bid < 320) {
        int tid = bid * 256 + threadIdx.x;          // 0 .. 81919
        int f   = tid >> 6;                         // fragment id 0..1279
        int l   = tid & 63;
        int gt  = f >> 4;
        int ks  = f & 15;
        int n   = (gt << 4) + (l & 15);
        int k0  = (ks << 5) + ((l >> 4) << 3);
        bf16x8 v;
        #pragma unroll
        for (int e = 0; e < 8; ++e) v[e] = (bf16)W[(size_t)(k0 + e) * 1280 + n];
        *reinterpret_cast<bf16x8*>(Wf + (size_t)tid * 8) = v;
        return;
    }
    int wid  = ((bid - 320) * 256 + threadIdx.x) >> 6;  // leaf index 0..32767
    int lane = threadIdx.x & 63;
    int b    = wid >> 11;
    int loc  = wid & 2047;
    int id   = b * PER + loc;
    int tok  = tokens[id];

    float4 e = *reinterpret_cast<const float4*>(emb + tok * DM + lane * 4);
    float ss = e.x * e.x + e.y * e.y + e.z * e.z + e.w * e.w;
    #pragma unroll
    for (int off = 32; off; off >>= 1) ss += __shfl_xor(ss, off);
    float scale = fminf(1.0f, 1.0f / fmaxf(sqrtf(ss), 1e-7f));
    e.x *= scale; e.y *= scale; e.z *= scale; e.w *= scale;

    int o = id * DM + lane * 4;
    *reinterpret_cast<float4*>(acts + o) = e;
    bf16x4 eb;
    eb.x = (bf16)e.x; eb.y = (bf16)e.y; eb.z = (bf16)e.z; eb.w = (bf16)e.w;
    *reinterpret_cast<bf16x4*>(actsb + o) = eb;
}

// ---------- Big-level kernel (Mt >= 128), templated on K-step count ----------
// Block: 256 thr (4 waves). Tile: 64 rows x 64 ucols (x 5 gates).
// LDS: A only, dbuf [2][KQ*4][64][8] bf16; B direct from Wfrag in regs.
// NKT=8 (BK=64, 16 KB LDS): R7-verified, best measured on level 1 (42.3 us).
// NKT=4 (BK=128, 32 KB LDS): R13-verified, best on levels 2-4.
// lb(256,2): VGPR budget for B-load buffering (R12: starving VGPRs for
// occupancy is a net loss). Scattered MFMA-layout epilogue (R20: LDS-bounced
// coalesced epilogue REGRESSED; WRITE_SIZE was already ideal).
template<int NKT>
__global__ __launch_bounds__(256, 2) void level_big(
        const bf16* __restrict__ actsb_in, const bf16* __restrict__ Wfrag,
        const float* __restrict__ bias, float* __restrict__ mem,
        float* __restrict__ acts, bf16* __restrict__ actsb_out,
        int off_k, int off_km1, int zmem) {
    constexpr int KQ  = 16 / NKT;          // 32-k slices per K-step
    constexpr int NLD = KQ;                // global_load_lds per K-step
    constexpr int BK  = KQ * 32;           // k-elems per K-step
    constexpr int NRG = 4;                 // row groups per wave
    __shared__ __align__(16) bf16 ldsA[2][KQ * 4][64][8];

    int t    = threadIdx.x;
    int lane = t & 63;
    int w    = t >> 6;
    int lo   = lane & 15;
    int hi   = lane >> 4;          // 0..3

    int rt    = blockIdx.x >> 2;   // 64-row tile within tree
    int uct   = blockIdx.x & 3;    // ucol tile (64 of 256)
    int b     = blockIdx.y;        // tree
    int rm    = rt << 6;
    int wslot = (uct << 2) + w;    // 0..15: this wave's 16-ucol slot

    const bf16* Abase = actsb_in + (size_t)(b * PER + off_km1) * DM;

    // A staging: slot s = i*256+t -> row = s&63, kblk8 = s>>6 (linear LDS dest)
    const bf16* aSrc[NLD];
    #pragma unroll
    for (int i = 0; i < NLD; ++i) {
        int s   = i * 256 + t;
        aSrc[i] = Abase + (size_t)(rm + (s & 63)) * KDIM + (s >> 6) * 8;
    }

    // B fragment base; gate g, kslice ks at + (((g<<8)|ks) << 9) elems
    const bf16* bbase = Wfrag + ((size_t)wslot << 13) + lane * 8;

    int ucol = (wslot << 4) + lo;
    float bi[NGATES];
    #pragma unroll
    for (int g = 0; g < NGATES; ++g) bi[g] = bias[g * DM + ucol];

    // prologue: stage K-tile 0 into buf 0
    #pragma unroll
    for (int i = 0; i < NLD; ++i)
        load_lds16(aSrc[i], &ldsA[0][0][0][0] + (i * 256 + t) * 8);

    f32x4 acc[NGATES][NRG] = {};

    __syncthreads();

    for (int kt = 0; kt < NKT; ++kt) {
        int cur = kt & 1;
        if (kt < NKT - 1) {                        // prefetch next K-tile (A)
            int ko = (kt + 1) * BK;
            #pragma unroll
            for (int i = 0; i < NLD; ++i)
                load_lds16(aSrc[i] + ko, &ldsA[cur ^ 1][0][0][0] + (i * 256 + t) * 8);
        }

        #pragma unroll
        for (int kq = 0; kq < KQ; ++kq) {
            int ks = kt * KQ + kq;                 // global 32-k slice [0,16)
            bf16x8 bb[NGATES];
            #pragma unroll
            for (int g = 0; g < NGATES; ++g)
                bb[g] = *reinterpret_cast<const bf16x8*>(bbase + (size_t)(((g << 8) | ks) << 9));
            #pragma unroll
            for (int rg = 0; rg < NRG; ++rg) {
                bf16x8 af = *reinterpret_cast<const bf16x8*>(&ldsA[cur][(kq << 2) + hi][(rg << 4) + lo][0]);
                #pragma unroll
                for (int g = 0; g < NGATES; ++g)
                    acc[g][rg] = __builtin_amdgcn_mfma_f32_16x16x32_bf16(af, bb[g], acc[g][rg], 0, 0, 0);
            }
        }
        __syncthreads();
    }

    int treebase = b * PER;
    #pragma unroll
    for (int rg = 0; rg < NRG; ++rg) {
        #pragma unroll
        for (int r = 0; r < 4; ++r) {
            int ml = rm + (rg << 4) + (hi << 2) + r;
            int id = treebase + off_k + ml;
            float cl = 0.0f, cr = 0.0f;
            if (!zmem) {
                int ch = (treebase + off_km1 + (ml << 1)) * DM + ucol;
                cl = mem[ch];
                cr = mem[ch + DM];
            }
            float gi = acc[0][rg][r] + bi[0];
            float gl = acc[1][rg][r] + bi[1];
            float gr = acc[2][rg][r] + bi[2];
            float go = acc[3][rg][r] + bi[3];
            float gu = acc[4][rg][r] + bi[4];
            float c  = sigf(gi) * tanh_fast(gu) + sigf(gl) * cl + sigf(gr) * cr;
            float h  = sigf(go) * tanh_fast(c);
            int oi = id * DM + ucol;
            acts[oi]      = h;
            mem[oi]       = c;
            actsb_out[oi] = (bf16)h;
        }
    }
}

// ---------- Split-K tail kernel (Mt < 128): 8-way K-split, 512 thr ----------
// Block = one 16-row x 16-ucol output tile (x 5 gates). Wave w computes
// k-slices {2w, 2w+1} -> 12 independent VMEM loads + 10 MFMA; partials
// reduced through LDS; wave 0 does the epilogue.
__global__ __launch_bounds__(512) void level_splitk(
        const bf16* __restrict__ actsb_in, const bf16* __restrict__ Wfrag,
        const float* __restrict__ bias, float* mem, float* acts, bf16* actsb_out,
        int off_k, int off_km1, int shift) {
    __shared__ f32x4 red[7][NGATES][64];

    int t    = threadIdx.x;
    int lane = t & 63;
    int w    = t >> 6;                 // 0..7
    int lo   = lane & 15;
    int hi   = lane >> 4;
    int tile = blockIdx.x >> 4;        // 16-row tile
    int uc   = blockIdx.x & 15;        // 16-ucol tile
    int m0   = tile << 4;
    int mask = (1 << shift) - 1;

    int mA   = m0 + lo;
    int rowA = (mA >> shift) * PER + off_km1 + ((mA & mask) << 1);
    const bf16* aptr  = actsb_in + (size_t)rowA * DM + hi * 8 + (w << 1) * 32;
    const bf16* bbase = Wfrag + ((size_t)uc << 13) + lane * 8;

    f32x4 acc[NGATES] = {};
    #pragma unroll
    for (int kk = 0; kk < 2; ++kk) {
        int kt = (w << 1) + kk;
        bf16x8 a = *reinterpret_cast<const bf16x8*>(aptr + kk * 32);
        #pragma unroll
        for (int g = 0; g < NGATES; ++g) {
            bf16x8 bb = *reinterpret_cast<const bf16x8*>(bbase + (size_t)(((g << 8) + kt) << 9));
            acc[g] = __builtin_amdgcn_mfma_f32_16x16x32_bf16(a, bb, acc[g], 0, 0, 0);
        }
    }

    if (w) {
        #pragma unroll
        for (int g = 0; g < NGATES; ++g) red[w - 1][g][lane] = acc[g];
    }
    __syncthreads();
    if (w == 0) {
        int ucol = (uc << 4) + lo;
        float bi[NGATES];
        #pragma unroll
        for (int g = 0; g < NGATES; ++g) {
            #pragma unroll
            for (int p = 0; p < 7; ++p) acc[g] += red[p][g][lane];
            bi[g] = bias[g * DM + ucol];
        }
        #pragma unroll
        for (int r = 0; r < 4; ++r) {
            int m   = m0 + (hi << 2) + r;
            int tb  = (m >> shift) * PER;
            int loc = m & mask;
            int id  = tb + off_k + loc;
            int ch  = (tb + off_km1 + (loc << 1)) * DM + ucol;
            float cl = mem[ch];
            float cr = mem[ch + DM];
            float gi = acc[0][r] + bi[0];
            float gl = acc[1][r] + bi[1];
            float gr = acc[2][r] + bi[2];
            float go = acc[3][r] + bi[3];
            float gu = acc[4][r] + bi[4];
            float c  = sigf(gi) * tanh_fast(gu) + sigf(gl) * cl + sigf(gr) * cr;
            float h  = sigf(go) * tanh_fast(c);
            int oi = id * DM + ucol;
            acts[oi]      = h;
            mem[oi]       = c;
            actsb_out[oi] = (bf16)h;
        }
    }
}

extern "C" void kernel_launch(void* const* d_in, const int* in_sizes, int n_in,
                              void* d_out, int out_size, void* d_ws, size_t ws_size,
                              hipStream_t stream) {
    (void)in_sizes; (void)n_in; (void)out_size; (void)ws_size;
    const int*   tokens = (const int*)d_in[0];
    const float* emb    = (const float*)d_in[8];
    const float* W      = (const float*)d_in[9];
    const float* bias   = (const float*)d_in[10];
    float* acts = (float*)d_out;

    char* ws = (char*)d_ws;
    bf16*  Wfrag = (bf16*)ws;                               // 1,310,720 B
    bf16*  actsb = (bf16*)(ws + 1310720);                   // 33,546,240 B
    float* mem   = (float*)(ws + 1310720 + 33546240);       // 67,092,480 B

    setup_kernel<<<dim3(320 + 8192), dim3(256), 0, stream>>>(
        W, Wfrag, tokens, emb, acts, actsb);

    int off_km1 = 0;
    for (int k = 1; k <= DEPTH; ++k) {
        int shift   = DEPTH - k;
        int Mt      = 1 << shift;            // rows per tree at this level
        int off_k   = off_km1 + (Mt << 1);
        int M_total = NTREES << shift;
        if (Mt >= 128) {
            dim3 grid((Mt / 64) * 4, NTREES);
            if (k == 1) {
                level_big<8><<<grid, dim3(256), 0, stream>>>(     // BK=64 (R7 best)
                    actsb, Wfrag, bias, mem, acts, actsb, off_k, off_km1, 1);
            } else {
                level_big<4><<<grid, dim3(256), 0, stream>>>(     // BK=128 (R13 best)
                    actsb, Wfrag, bias, mem, acts, actsb, off_k, off_km1, 0);
            }
        } else {
            level_splitk<<<dim3(M_total), dim3(512), 0, stream>>>(
                actsb, Wfrag, bias, mem, acts, actsb, off_k, off_km1, shift);
        }
        off_km1 = off_k;
    }
}